// Round 1
// baseline (544.123 us; speedup 1.0000x reference)
//
#include <hip/hip_runtime.h>
#include <math.h>

// ---------------------------------------------------------------------------
// 2-layer GCN: h1 = leaky(norm-agg(x@W1)+b1); out = log_softmax(norm-agg(h1@W2)+b2)
// norm-agg uses symmetric normalization dinv[s]*dinv[d], deg from dst (+self loop).
// Strategy: build CSR by dst each call (hist -> scan -> scatter), then pull-based
// wave-per-node aggregation (no float atomics, deterministic per-run order).
// ---------------------------------------------------------------------------

__global__ void zero_kernel(int* __restrict__ p, int n) {
  int i = blockIdx.x * blockDim.x + threadIdx.x;
  if (i < n) p[i] = 0;
}

__global__ void hist_kernel(const int* __restrict__ dst, int E, int* __restrict__ cnt) {
  int i = blockIdx.x * blockDim.x + threadIdx.x;
  if (i < E) atomicAdd(&cnt[dst[i]], 1);
}

__global__ void dinv_kernel(const int* __restrict__ cnt, float* __restrict__ dinv, int n) {
  int i = blockIdx.x * blockDim.x + threadIdx.x;
  if (i < n) dinv[i] = rsqrtf((float)(cnt[i] + 1));  // +1 self loop; deg >= 1 always
}

// Block-level exclusive scan of cnt (256/block); partial -> row_start, block total -> bsum
__global__ void scan1_kernel(const int* __restrict__ cnt, int n,
                             int* __restrict__ partial, int* __restrict__ bsum) {
  __shared__ int sm[256];
  int tid = threadIdx.x;
  int i = blockIdx.x * 256 + tid;
  int v = (i < n) ? cnt[i] : 0;
  sm[tid] = v;
  __syncthreads();
  for (int off = 1; off < 256; off <<= 1) {
    int a = sm[tid];
    int b = (tid >= off) ? sm[tid - off] : 0;
    __syncthreads();
    sm[tid] = a + b;
    __syncthreads();
  }
  int inc = sm[tid];
  if (i < n) partial[i] = inc - v;           // exclusive-within-block
  if (tid == 255) bsum[blockIdx.x] = inc;    // block total
}

// Scan of block sums (single block, nb <= 512; N=100k -> nb=391)
__global__ void scan2_kernel(const int* __restrict__ bsum, int nb, int* __restrict__ boffs) {
  __shared__ int sm[512];
  int tid = threadIdx.x;
  int v = (tid < nb) ? bsum[tid] : 0;
  sm[tid] = v;
  __syncthreads();
  for (int off = 1; off < 512; off <<= 1) {
    int a = sm[tid];
    int b = (tid >= off) ? sm[tid - off] : 0;
    __syncthreads();
    sm[tid] = a + b;
    __syncthreads();
  }
  boffs[tid] = sm[tid] - v;  // exclusive
}

// Add block offsets in-place; init cursor; set row_start[n] = E
__global__ void scan3_kernel(const int* __restrict__ boffs, int n, int E,
                             int* __restrict__ row_start, int* __restrict__ cursor) {
  int i = blockIdx.x * 256 + threadIdx.x;
  if (i < n) {
    int r = row_start[i] + boffs[blockIdx.x];
    row_start[i] = r;
    cursor[i] = r;
  }
  if (i == 0) row_start[n] = E;
}

__global__ void scatter_kernel(const int* __restrict__ src, const int* __restrict__ dst,
                               int E, int* __restrict__ cursor, int* __restrict__ csr) {
  int i = blockIdx.x * blockDim.x + threadIdx.x;
  if (i < E) {
    int pos = atomicAdd(&cursor[dst[i]], 1);
    csr[pos] = src[i];
  }
}

// h1[row][f] = sum_k x[row][k] * W1[k][f].  Thread-per-row: W1 indices are
// lane-invariant -> scalar (SMEM) loads; 64 fp32 accumulators in VGPRs.
__global__ __launch_bounds__(256) void gemm1_kernel(const float* __restrict__ x,
                                                    const float* __restrict__ W1,
                                                    float* __restrict__ h1, int n) {
  int row = blockIdx.x * 256 + threadIdx.x;
  if (row >= n) return;
  const float4* x4 = (const float4*)(x + (size_t)row * 128);
  float acc[64];
#pragma unroll
  for (int f = 0; f < 64; ++f) acc[f] = 0.f;
#pragma unroll 4
  for (int k4 = 0; k4 < 32; ++k4) {
    float4 xv = x4[k4];
#pragma unroll
    for (int j = 0; j < 4; ++j) {
      float xs = (j == 0) ? xv.x : (j == 1) ? xv.y : (j == 2) ? xv.z : xv.w;
      const float* wrow = W1 + (size_t)(k4 * 4 + j) * 64;
#pragma unroll
      for (int f = 0; f < 64; ++f) acc[f] = fmaf(xs, wrow[f], acc[f]);
    }
  }
  float4* o4 = (float4*)(h1 + (size_t)row * 64);
#pragma unroll
  for (int f4 = 0; f4 < 16; ++f4)
    o4[f4] = make_float4(acc[4 * f4], acc[4 * f4 + 1], acc[4 * f4 + 2], acc[4 * f4 + 3]);
}

// Wave-per-node aggregation over 64 features (lane = feature), fused with
// bias + leaky_relu + 64x16 second-layer linear (LDS round-trip in-wave).
__global__ __launch_bounds__(256) void agg1_kernel(const float* __restrict__ h1,
                                                   const float* __restrict__ dinv,
                                                   const int* __restrict__ row_start,
                                                   const int* __restrict__ csr,
                                                   const float* __restrict__ b1,
                                                   const float* __restrict__ W2,
                                                   float* __restrict__ t, int n) {
  __shared__ float W2s[64 * 17];  // padded rows: +17 stride breaks bank conflicts
  __shared__ float a_s[4][64];
  for (int i = threadIdx.x; i < 1024; i += 256)
    W2s[(i >> 4) * 17 + (i & 15)] = W2[i];
  __syncthreads();

  int wave = threadIdx.x >> 6, lane = threadIdx.x & 63;
  int v = blockIdx.x * 4 + wave;
  bool valid = (v < n);
  int vc = valid ? v : 0;

  float dv = dinv[vc];
  float acc = dv * h1[(size_t)vc * 64 + lane];       // self loop (dv^2 after final *dv)
  int e0 = row_start[vc], e1 = row_start[vc + 1];
  for (int i = e0; i < e1; ++i) {
    int s = csr[i];                                   // wave-uniform -> scalar load
    acc = fmaf(dinv[s], h1[(size_t)s * 64 + lane], acc);
  }
  float z = fmaf(dv, acc, b1[lane]);
  float a = fmaxf(z, 0.2f * z);                       // leaky_relu slope 0.2
  a_s[wave][lane] = a;
  __threadfence_block();                              // LDS visibility within wave

  // t[v][j] = sum_f a[f] * W2[f][j]; lane handles j = lane&15 over 16 f's, then
  // butterfly-combine the 4 f-groups.
  int j = lane & 15, fb = (lane >> 4) << 4;
  float p = 0.f;
#pragma unroll
  for (int q = 0; q < 16; ++q) {
    int f = fb + q;
    p = fmaf(a_s[wave][f], W2s[f * 17 + j], p);
  }
  p += __shfl_xor(p, 16, 64);
  p += __shfl_xor(p, 32, 64);
  if (valid && lane < 16) t[(size_t)v * 16 + j] = p;
}

// 16 lanes per node: aggregate 16 features, + b2, log_softmax across the 16 lanes.
__global__ __launch_bounds__(256) void agg2_kernel(const float* __restrict__ t,
                                                   const float* __restrict__ dinv,
                                                   const int* __restrict__ row_start,
                                                   const int* __restrict__ csr,
                                                   const float* __restrict__ b2,
                                                   float* __restrict__ out, int n) {
  int idx = blockIdx.x * 256 + threadIdx.x;
  int v = idx >> 4, j = idx & 15;
  if (v >= n) return;
  float dv = dinv[v];
  float acc = dv * t[(size_t)v * 16 + j];
  int e0 = row_start[v], e1 = row_start[v + 1];
  for (int i = e0; i < e1; ++i) {
    int s = csr[i];
    acc = fmaf(dinv[s], t[(size_t)s * 16 + j], acc);
  }
  float z = fmaf(dv, acc, b2[j]);
  float m = z;
#pragma unroll
  for (int w = 1; w < 16; w <<= 1) m = fmaxf(m, __shfl_xor(m, w, 16));
  float p = expf(z - m);
  float ssum = p;
#pragma unroll
  for (int w = 1; w < 16; w <<= 1) ssum += __shfl_xor(ssum, w, 16);
  out[(size_t)v * 16 + j] = (z - m) - logf(ssum);
}

extern "C" void kernel_launch(void* const* d_in, const int* in_sizes, int n_in,
                              void* d_out, int out_size, void* d_ws, size_t ws_size,
                              hipStream_t stream) {
  const float* x = (const float*)d_in[0];
  const int* edge_index = (const int*)d_in[1];
  const float* W1 = (const float*)d_in[2];
  const float* b1 = (const float*)d_in[3];
  const float* W2 = (const float*)d_in[4];
  const float* b2 = (const float*)d_in[5];
  float* out = (float*)d_out;

  int N_ = in_sizes[0] / 128;
  int E_ = in_sizes[1] / 2;
  const int* src = edge_index;
  const int* dst = edge_index + E_;

  // Workspace carve-up (poisoned 0xAA each call; everything below is fully
  // (re)initialized each launch). Total ~40 MB.
  char* ws = (char*)d_ws;
  size_t off = 0;
  auto take = [&](size_t bytes) {
    void* p = ws + off;
    off += (bytes + 255) & ~(size_t)255;
    return p;
  };
  float* h1 = (float*)take((size_t)N_ * 64 * 4);
  float* t = (float*)take((size_t)N_ * 16 * 4);
  float* dinv = (float*)take((size_t)N_ * 4);
  int* cnt = (int*)take((size_t)N_ * 4);
  int* row_start = (int*)take(((size_t)N_ + 1) * 4);
  int* cursor = (int*)take((size_t)N_ * 4);
  int* csr = (int*)take((size_t)E_ * 4);
  int* bsum = (int*)take(512 * 4);
  int* boffs = (int*)take(512 * 4);
  (void)ws_size;

  int nbN = (N_ + 255) / 256;   // 391 (must be <= 512 for scan2)
  int nbE = (E_ + 255) / 256;

  zero_kernel<<<nbN, 256, 0, stream>>>(cnt, N_);
  hist_kernel<<<nbE, 256, 0, stream>>>(dst, E_, cnt);
  dinv_kernel<<<nbN, 256, 0, stream>>>(cnt, dinv, N_);
  scan1_kernel<<<nbN, 256, 0, stream>>>(cnt, N_, row_start, bsum);
  scan2_kernel<<<1, 512, 0, stream>>>(bsum, nbN, boffs);
  scan3_kernel<<<nbN, 256, 0, stream>>>(boffs, N_, E_, row_start, cursor);
  scatter_kernel<<<nbE, 256, 0, stream>>>(src, dst, E_, cursor, csr);
  gemm1_kernel<<<nbN, 256, 0, stream>>>(x, W1, h1, N_);
  agg1_kernel<<<(N_ + 3) / 4, 256, 0, stream>>>(h1, dinv, row_start, csr, b1, W2, t, N_);
  agg2_kernel<<<(N_ * 16 + 255) / 256, 256, 0, stream>>>(t, dinv, row_start, csr, b2, out, N_);
}

// Round 2
// 450.188 us; speedup vs baseline: 1.2087x; 1.2087x over previous
//
#include <hip/hip_runtime.h>
#include <math.h>

// ---------------------------------------------------------------------------
// 2-layer GCN. R2: latency-bound gather fix.
//  - dinv folded into stored rows (h1s = dinv*h1, t = dinv*h2): edge loops are
//    pure sums, no per-edge dinv load in the dependent chain.
//  - edge loops unrolled x4 with independent accumulators: 4 row-gathers in
//    flight per wave instead of 1.
// ---------------------------------------------------------------------------

__global__ void zero_kernel(int* __restrict__ p, int n) {
  int i = blockIdx.x * blockDim.x + threadIdx.x;
  if (i < n) p[i] = 0;
}

__global__ void hist_kernel(const int* __restrict__ dst, int E, int* __restrict__ cnt) {
  int i = blockIdx.x * blockDim.x + threadIdx.x;
  if (i < E) atomicAdd(&cnt[dst[i]], 1);
}

__global__ void dinv_kernel(const int* __restrict__ cnt, float* __restrict__ dinv, int n) {
  int i = blockIdx.x * blockDim.x + threadIdx.x;
  if (i < n) dinv[i] = rsqrtf((float)(cnt[i] + 1));  // +1 self loop
}

__global__ void scan1_kernel(const int* __restrict__ cnt, int n,
                             int* __restrict__ partial, int* __restrict__ bsum) {
  __shared__ int sm[256];
  int tid = threadIdx.x;
  int i = blockIdx.x * 256 + tid;
  int v = (i < n) ? cnt[i] : 0;
  sm[tid] = v;
  __syncthreads();
  for (int off = 1; off < 256; off <<= 1) {
    int a = sm[tid];
    int b = (tid >= off) ? sm[tid - off] : 0;
    __syncthreads();
    sm[tid] = a + b;
    __syncthreads();
  }
  int inc = sm[tid];
  if (i < n) partial[i] = inc - v;
  if (tid == 255) bsum[blockIdx.x] = inc;
}

__global__ void scan2_kernel(const int* __restrict__ bsum, int nb, int* __restrict__ boffs) {
  __shared__ int sm[512];
  int tid = threadIdx.x;
  int v = (tid < nb) ? bsum[tid] : 0;
  sm[tid] = v;
  __syncthreads();
  for (int off = 1; off < 512; off <<= 1) {
    int a = sm[tid];
    int b = (tid >= off) ? sm[tid - off] : 0;
    __syncthreads();
    sm[tid] = a + b;
    __syncthreads();
  }
  boffs[tid] = sm[tid] - v;
}

__global__ void scan3_kernel(const int* __restrict__ boffs, int n, int E,
                             int* __restrict__ row_start, int* __restrict__ cursor) {
  int i = blockIdx.x * 256 + threadIdx.x;
  if (i < n) {
    int r = row_start[i] + boffs[blockIdx.x];
    row_start[i] = r;
    cursor[i] = r;
  }
  if (i == 0) row_start[n] = E;
}

__global__ void scatter_kernel(const int* __restrict__ src, const int* __restrict__ dst,
                               int E, int* __restrict__ cursor, int* __restrict__ csr) {
  int i = blockIdx.x * blockDim.x + threadIdx.x;
  if (i < E) {
    int pos = atomicAdd(&cursor[dst[i]], 1);
    csr[pos] = src[i];
  }
}

// h1s[row][f] = dinv[row] * sum_k x[row][k] * W1[k][f]
__global__ __launch_bounds__(256) void gemm1_kernel(const float* __restrict__ x,
                                                    const float* __restrict__ W1,
                                                    const float* __restrict__ dinv,
                                                    float* __restrict__ h1s, int n) {
  int row = blockIdx.x * 256 + threadIdx.x;
  if (row >= n) return;
  const float4* x4 = (const float4*)(x + (size_t)row * 128);
  float acc[64];
#pragma unroll
  for (int f = 0; f < 64; ++f) acc[f] = 0.f;
#pragma unroll 4
  for (int k4 = 0; k4 < 32; ++k4) {
    float4 xv = x4[k4];
#pragma unroll
    for (int j = 0; j < 4; ++j) {
      float xs = (j == 0) ? xv.x : (j == 1) ? xv.y : (j == 2) ? xv.z : xv.w;
      const float* wrow = W1 + (size_t)(k4 * 4 + j) * 64;
#pragma unroll
      for (int f = 0; f < 64; ++f) acc[f] = fmaf(xs, wrow[f], acc[f]);
    }
  }
  float dv = dinv[row];
  float4* o4 = (float4*)(h1s + (size_t)row * 64);
#pragma unroll
  for (int f4 = 0; f4 < 16; ++f4)
    o4[f4] = make_float4(dv * acc[4 * f4], dv * acc[4 * f4 + 1],
                         dv * acc[4 * f4 + 2], dv * acc[4 * f4 + 3]);
}

// Wave-per-node: acc = h1s[v] + sum h1s[csr[i]] (x4 unrolled), then
// z = dv*acc + b1, leaky_relu, 64x16 linear, t[v] = dv2-scaled output.
__global__ __launch_bounds__(256) void agg1_kernel(const float* __restrict__ h1s,
                                                   const float* __restrict__ dinv,
                                                   const int* __restrict__ row_start,
                                                   const int* __restrict__ csr,
                                                   const float* __restrict__ b1,
                                                   const float* __restrict__ W2,
                                                   float* __restrict__ t, int n) {
  __shared__ float W2s[64 * 17];
  __shared__ float a_s[4][64];
  for (int i = threadIdx.x; i < 1024; i += 256)
    W2s[(i >> 4) * 17 + (i & 15)] = W2[i];
  __syncthreads();

  int wave = threadIdx.x >> 6, lane = threadIdx.x & 63;
  int v = blockIdx.x * 4 + wave;
  bool valid = (v < n);
  int vc = valid ? v : 0;

  float dv = dinv[vc];
  int e0 = row_start[vc], e1 = row_start[vc + 1];
  float acc0 = h1s[(size_t)vc * 64 + lane];  // self loop (already dinv-scaled)
  float acc1 = 0.f, acc2 = 0.f, acc3 = 0.f;
  int i = e0;
  for (; i + 3 < e1; i += 4) {
    int s0 = csr[i], s1 = csr[i + 1], s2 = csr[i + 2], s3 = csr[i + 3];
    float g0 = h1s[(size_t)s0 * 64 + lane];
    float g1 = h1s[(size_t)s1 * 64 + lane];
    float g2 = h1s[(size_t)s2 * 64 + lane];
    float g3 = h1s[(size_t)s3 * 64 + lane];
    acc0 += g0; acc1 += g1; acc2 += g2; acc3 += g3;
  }
  for (; i < e1; ++i) acc0 += h1s[(size_t)csr[i] * 64 + lane];
  float acc = (acc0 + acc1) + (acc2 + acc3);

  float z = fmaf(dv, acc, b1[lane]);
  float a = fmaxf(z, 0.2f * z);  // leaky_relu 0.2
  a_s[wave][lane] = a;
  __threadfence_block();

  int j = lane & 15, fb = (lane >> 4) << 4;
  float p = 0.f;
#pragma unroll
  for (int q = 0; q < 16; ++q) {
    int f = fb + q;
    p = fmaf(a_s[wave][f], W2s[f * 17 + j], p);
  }
  p += __shfl_xor(p, 16, 64);
  p += __shfl_xor(p, 32, 64);
  if (valid && lane < 16) t[(size_t)v * 16 + j] = dv * p;  // fold dinv for layer 2
}

// 16 lanes per node: acc = t[v] + sum t[csr[i]] (x4), z = dv*acc + b2, log_softmax.
__global__ __launch_bounds__(256) void agg2_kernel(const float* __restrict__ t,
                                                   const float* __restrict__ dinv,
                                                   const int* __restrict__ row_start,
                                                   const int* __restrict__ csr,
                                                   const float* __restrict__ b2,
                                                   float* __restrict__ out, int n) {
  int idx = blockIdx.x * 256 + threadIdx.x;
  int v = idx >> 4, j = idx & 15;
  if (v >= n) return;
  float dv = dinv[v];
  int e0 = row_start[v], e1 = row_start[v + 1];
  float acc0 = t[(size_t)v * 16 + j];  // self loop (already dinv-scaled)
  float acc1 = 0.f, acc2 = 0.f, acc3 = 0.f;
  int i = e0;
  for (; i + 3 < e1; i += 4) {
    int s0 = csr[i], s1 = csr[i + 1], s2 = csr[i + 2], s3 = csr[i + 3];
    float g0 = t[(size_t)s0 * 16 + j];
    float g1 = t[(size_t)s1 * 16 + j];
    float g2 = t[(size_t)s2 * 16 + j];
    float g3 = t[(size_t)s3 * 16 + j];
    acc0 += g0; acc1 += g1; acc2 += g2; acc3 += g3;
  }
  for (; i < e1; ++i) acc0 += t[(size_t)csr[i] * 16 + j];
  float z = fmaf(dv, (acc0 + acc1) + (acc2 + acc3), b2[j]);

  float m = z;
#pragma unroll
  for (int w = 1; w < 16; w <<= 1) m = fmaxf(m, __shfl_xor(m, w, 16));
  float p = expf(z - m);
  float ssum = p;
#pragma unroll
  for (int w = 1; w < 16; w <<= 1) ssum += __shfl_xor(ssum, w, 16);
  out[(size_t)v * 16 + j] = (z - m) - logf(ssum);
}

extern "C" void kernel_launch(void* const* d_in, const int* in_sizes, int n_in,
                              void* d_out, int out_size, void* d_ws, size_t ws_size,
                              hipStream_t stream) {
  const float* x = (const float*)d_in[0];
  const int* edge_index = (const int*)d_in[1];
  const float* W1 = (const float*)d_in[2];
  const float* b1 = (const float*)d_in[3];
  const float* W2 = (const float*)d_in[4];
  const float* b2 = (const float*)d_in[5];
  float* out = (float*)d_out;

  int N_ = in_sizes[0] / 128;
  int E_ = in_sizes[1] / 2;
  const int* src = edge_index;
  const int* dst = edge_index + E_;

  char* ws = (char*)d_ws;
  size_t off = 0;
  auto take = [&](size_t bytes) {
    void* p = ws + off;
    off += (bytes + 255) & ~(size_t)255;
    return p;
  };
  float* h1s = (float*)take((size_t)N_ * 64 * 4);
  float* t = (float*)take((size_t)N_ * 16 * 4);
  float* dinv = (float*)take((size_t)N_ * 4);
  int* cnt = (int*)take((size_t)N_ * 4);
  int* row_start = (int*)take(((size_t)N_ + 1) * 4);
  int* cursor = (int*)take((size_t)N_ * 4);
  int* csr = (int*)take((size_t)E_ * 4);
  int* bsum = (int*)take(512 * 4);
  int* boffs = (int*)take(512 * 4);
  (void)ws_size;

  int nbN = (N_ + 255) / 256;
  int nbE = (E_ + 255) / 256;

  zero_kernel<<<nbN, 256, 0, stream>>>(cnt, N_);
  hist_kernel<<<nbE, 256, 0, stream>>>(dst, E_, cnt);
  dinv_kernel<<<nbN, 256, 0, stream>>>(cnt, dinv, N_);
  scan1_kernel<<<nbN, 256, 0, stream>>>(cnt, N_, row_start, bsum);
  scan2_kernel<<<1, 512, 0, stream>>>(bsum, nbN, boffs);
  scan3_kernel<<<nbN, 256, 0, stream>>>(boffs, N_, E_, row_start, cursor);
  scatter_kernel<<<nbE, 256, 0, stream>>>(src, dst, E_, cursor, csr);
  gemm1_kernel<<<nbN, 256, 0, stream>>>(x, W1, dinv, h1s, N_);
  agg1_kernel<<<(N_ + 3) / 4, 256, 0, stream>>>(h1s, dinv, row_start, csr, b1, W2, t, N_);
  agg2_kernel<<<(N_ * 16 + 255) / 256, 256, 0, stream>>>(t, dinv, row_start, csr, b2, out, N_);
}